// Round 6
// baseline (468.222 us; speedup 1.0000x reference)
//
#include <hip/hip_runtime.h>
#include <math.h>

// Causal self-attention, B=4 T=2048 E=1024 H=16 D=64.
// R13: qkv_gemm = R7 verbatim (79us, twice-proven). cvt unchanged.
//   attn_fwd REBUILT for uniform occupancy: R12 counters showed 18.3% occupancy
//   (5.9 waves/CU), MfmaUtil 17.6, per-SIMD VALU ~12% -> ~70% idle, latency-
//   bound. Cause: block lengths 2qt+2 in [2,32] tiles; per-CU concurrency
//   decays to ~2.1 blocks average. Fix: 64-row q-tiles paired (j, 31-j) ->
//   EVERY block = 33 key-tiles. 1024 equal blocks = 4 blocks/CU for the whole
//   kernel (LDS 40KB x4 = exactly 160KiB). Wave owns 16 q-rows per phase
//   (1 qg/tile); kf/vf amortization halves (LDS BW ~35%, headroom) but
//   resident waves ~2x - the binding constraint. Mask branch wave-uniform,
//   fires exactly on each phase's final tile (no ghost work). Tree-sum kept.
//   No setprio (R11: harmful in barrier-locked blocks).

using short8 = __attribute__((ext_vector_type(8))) short;
using f32x4  = __attribute__((ext_vector_type(4))) float;

__device__ __forceinline__ ushort f2bf(float f) {
    union { float f; unsigned u; } x{f};
    unsigned r = x.u + 0x7fffu + ((x.u >> 16) & 1u);   // RNE
    return (ushort)(r >> 16);
}
// pack two f32 -> two bf16 (round-half-up in magnitude; <=1 ulp) in 3 VALU
__device__ __forceinline__ unsigned pack_bf16_ru(float a, float b) {
    union { float f; unsigned u; } x{a}, y{b};
    return __builtin_amdgcn_perm(y.u + 0x8000u, x.u + 0x8000u, 0x07060302u);
}

__device__ __forceinline__ void gload_lds16(const void* g, void* l) {
    __builtin_amdgcn_global_load_lds(
        (const __attribute__((address_space(1))) void*)g,
        (__attribute__((address_space(3))) void*)l, 16, 0, 0);
}

// ---------------- fp32 -> bf16 convert (x and w in one launch) ----------------
__global__ void cvt_all(const float* __restrict__ x, const float* __restrict__ w,
                        ushort* __restrict__ xb, ushort* __restrict__ wb) {
    int i = blockIdx.x * blockDim.x + threadIdx.x;
    const float* src; ushort* dst; int j;
    if (i < 2097152) { src = x; dst = xb; j = i; }
    else             { src = w; dst = wb; j = i - 2097152; if (j >= 786432) return; }
    float4 v = ((const float4*)src)[j];
    ushort4 o;
    o.x = f2bf(v.x); o.y = f2bf(v.y); o.z = f2bf(v.z); o.w = f2bf(v.w);
    ((ushort4*)dst)[j] = o;
}

// ---------------- QKV GEMM ----------------
// M=8192 N=3072 K=1024. 128x128 tile, BK=64, global_load_lds + swizzle.
// Grid 1536 1-D: xcd=id&7 owns bm slab xcd*8..+7 (A-tiles filled once per L2).
__global__ __launch_bounds__(256) void qkv_gemm(
    const ushort* __restrict__ A, const ushort* __restrict__ W,
    const float* __restrict__ bias,
    ushort* __restrict__ Qo, ushort* __restrict__ Ko, ushort* __restrict__ Vt)
{
    __shared__ ushort As[128 * 64];
    __shared__ ushort Ws[128 * 64];
    const int id = (int)blockIdx.x;
    const int xcd = id & 7, s = id >> 3;          // s: 0..191
    const int bm = xcd * 8 + (s & 7);             // 8-row slab per XCD
    const int bn = s >> 3;                        // 0..23
    const int tid = threadIdx.x;
    const int wave = tid >> 6, lane = tid & 63;
    const int quad = lane >> 4, l16 = lane & 15, l7 = l16 & 7;
    const int wm = (wave >> 1) * 64, wn = (wave & 1) * 64;

    const ushort* Abase = A + (size_t)(bm * 128) * 1024;
    const ushort* Wbase = W + (size_t)(bn * 128) * 1024;

    f32x4 acc[4][4];
#pragma unroll
    for (int i = 0; i < 4; i++)
#pragma unroll
        for (int j = 0; j < 4; j++) acc[i][j] = (f32x4){0.f, 0.f, 0.f, 0.f};

    for (int k0 = 0; k0 < 1024; k0 += 64) {
        __syncthreads();
#pragma unroll
        for (int j = 0; j < 4; j++) {
            const int rb = wave * 32 + j * 8;
            const int r  = rb + (lane >> 3);
            const int cc = (lane & 7) ^ (r & 7);
            gload_lds16(Abase + (size_t)r * 1024 + k0 + cc * 8, &As[rb * 64]);
            gload_lds16(Wbase + (size_t)r * 1024 + k0 + cc * 8, &Ws[rb * 64]);
        }
        __syncthreads();
        short8 af[4][2], wf[4][2];
#pragma unroll
        for (int t = 0; t < 4; t++)
#pragma unroll
            for (int kg = 0; kg < 2; kg++) {
                const int pc = ((kg * 4 + quad) ^ l7) * 8;
                af[t][kg] = *(const short8*)&As[(wm + t * 16 + l16) * 64 + pc];
                wf[t][kg] = *(const short8*)&Ws[(wn + t * 16 + l16) * 64 + pc];
            }
#pragma unroll
        for (int kg = 0; kg < 2; kg++)
#pragma unroll
            for (int tm = 0; tm < 4; tm++)
#pragma unroll
                for (int tn = 0; tn < 4; tn++)
                    acc[tm][tn] = __builtin_amdgcn_mfma_f32_16x16x32_bf16(af[tm][kg], wf[tn][kg], acc[tm][tn], 0, 0, 0);
    }

    const float SCALE_Q = 0.125f * 1.4426950408889634f;
#pragma unroll
    for (int tn = 0; tn < 4; tn++) {
        const int n = bn * 128 + wn + tn * 16 + l16;
        const float bv = bias[n];
#pragma unroll
        for (int tm = 0; tm < 4; tm++) {
            const int m0 = bm * 128 + wm + tm * 16 + quad * 4;
            const int b0 = m0 >> 11, t0 = m0 & 2047;
            if (n < 1024) {
                const int h = n >> 6, d = n & 63;
#pragma unroll
                for (int r = 0; r < 4; r++)
                    Qo[((size_t)(b0 * 16 + h) * 2048 + t0 + r) * 64 + d] = f2bf((acc[tm][tn][r] + bv) * SCALE_Q);
            } else if (n < 2048) {
                const int c = n - 1024, h = c >> 6, d = c & 63;
#pragma unroll
                for (int r = 0; r < 4; r++)
                    Ko[((size_t)(b0 * 16 + h) * 2048 + t0 + r) * 64 + d] = f2bf(acc[tm][tn][r] + bv);
            } else {
                const int c = n - 2048, h = c >> 6, d = c & 63;
                uint2 pk;
                pk.x = pack_bf16_ru(acc[tm][tn][0] + bv, acc[tm][tn][1] + bv);
                pk.y = pack_bf16_ru(acc[tm][tn][2] + bv, acc[tm][tn][3] + bv);
                *(uint2*)&Vt[((size_t)(b0 * 16 + h) * 64 + d) * 2048 + t0] = pk;
            }
        }
    }
}

// ---------------- Flash attention (fixed-max softmax, paired 64-row q-tiles) ----------------
// 1024 blocks: bh = id&63 (id%8 = bh%8 -> head's blocks on one XCD), pr = id>>6.
// Block handles q-tiles qtA=pr (64 rows) and qtB=31-pr: total key-tiles =
// (pr+1) + (32-pr) = 33 for EVERY block -> 4 equal blocks/CU all kernel long.
// Wave w owns q-rows qt*64 + w*16 .. +15 in each phase (one qg per tile).
__global__ __launch_bounds__(256) void attn_fwd(
    const ushort* __restrict__ Q, const ushort* __restrict__ K,
    const ushort* __restrict__ Vt, float* __restrict__ out)
{
    __shared__ ushort Ks[2][64 * 64];
    __shared__ ushort Vs[2][64 * 64];
    __shared__ ushort Ps[4][16 * 64];   // per-wave
    const int id = (int)blockIdx.x;     // 1024 blocks
    const int bh = id & 63;
    const int pr = id >> 6;             // 0..15
    const int qtA = pr, qtB = 31 - pr;  // 64-row q-tiles, paired for equal work
    const int na = qtA + 1;             // phase-A tiles; total tiles = 33
    const int b = bh >> 4, h = bh & 15;
    const int wave = threadIdx.x >> 6, lane = threadIdx.x & 63;
    const int quad = lane >> 4, l16 = lane & 15, l7 = l16 & 7;

    const ushort* Kbh = K  + (size_t)bh * 2048 * 64;
    const ushort* Vbh = Vt + (size_t)bh * 64 * 2048;
    ushort* Pw = Ps[wave];

    int qb[2];
    qb[0] = qtA * 64 + wave * 16;
    qb[1] = qtB * 64 + wave * 16;

    short8 qf[2][2];
#pragma unroll
    for (int ph = 0; ph < 2; ph++) {
        const ushort* Qp = Q + ((size_t)bh * 2048 + qb[ph] + l16) * 64;
        qf[ph][0] = *(const short8*)(Qp + quad * 8);
        qf[ph][1] = *(const short8*)(Qp + 32 + quad * 8);
    }

    f32x4 o[2][4];
#pragma unroll
    for (int ph = 0; ph < 2; ph++)
#pragma unroll
        for (int dg = 0; dg < 4; dg++) o[ph][dg] = (f32x4){0.f, 0.f, 0.f, 0.f};
    float lsum[2] = {0.f, 0.f};

#define STAGE(k0_, bf_)                                                              \
    {                                                                                \
        _Pragma("unroll")                                                            \
        for (int j = 0; j < 2; j++) {                                                \
            const int rb = wave * 16 + j * 8;                                        \
            const int r  = rb + (lane >> 3);                                         \
            const int cc = (lane & 7) ^ (r & 7);                                     \
            gload_lds16(Kbh + (size_t)((k0_) + r) * 64 + cc * 8, &Ks[bf_][rb * 64]); \
            gload_lds16(Vbh + (size_t)r * 2048 + (k0_) + cc * 8, &Vs[bf_][rb * 64]); \
        }                                                                            \
    }

    STAGE(0, 0);
    int buf = 0;
    for (int i = 0; i < 33; ++i, buf ^= 1) {
        const int ph = (i >= na) ? 1 : 0;
        const int k0 = ((ph ? i - na : i)) * 64;
        __syncthreads();
        if (i + 1 < 33) {
            const int j = i + 1;
            const int nk0 = ((j >= na) ? j - na : j) * 64;
            STAGE(nk0, buf ^ 1);
        }

        short8 kf[4][2];
#pragma unroll
        for (int t = 0; t < 4; t++)
#pragma unroll
            for (int dh = 0; dh < 2; dh++)
                kf[t][dh] = *(const short8*)&Ks[buf][(t * 16 + l16) * 64 + (((dh * 4 + quad) ^ l7) * 8)];
        short8 vf[2][4];
#pragma unroll
        for (int kg = 0; kg < 2; kg++) {
            const int pc = ((kg * 4 + quad) ^ l7) * 8;
#pragma unroll
            for (int dg = 0; dg < 4; dg++)
                vf[kg][dg] = *(const short8*)&Vs[buf][(dg * 16 + l16) * 64 + pc];
        }

        // QK^T for this tile's single active q-group (phase ph)
        f32x4 sc[4];
#pragma unroll
        for (int t = 0; t < 4; t++) {
            f32x4 z = (f32x4){0.f, 0.f, 0.f, 0.f};
            z = __builtin_amdgcn_mfma_f32_16x16x32_bf16(kf[t][0], qf[ph][0], z, 0, 0, 0);
            z = __builtin_amdgcn_mfma_f32_16x16x32_bf16(kf[t][1], qf[ph][1], z, 0, 0, 0);
            sc[t] = z;
        }
        const int q = qb[ph] + l16;
        float p[16];
        if (k0 + 63 > qb[ph]) {          // wave-uniform; true only on the phase's last tile
#pragma unroll
            for (int t = 0; t < 4; t++)
#pragma unroll
                for (int r = 0; r < 4; r++) {
                    const int key = k0 + t * 16 + quad * 4 + r;
                    const float sv = (key <= q) ? sc[t][r] : -INFINITY;
                    p[t * 4 + r] = __builtin_amdgcn_exp2f(sv);
                }
        } else {
#pragma unroll
            for (int t = 0; t < 4; t++)
#pragma unroll
                for (int r = 0; r < 4; r++)
                    p[t * 4 + r] = __builtin_amdgcn_exp2f(sc[t][r]);
        }
        // tree-sum
        {
            const float s0 = (p[0] + p[1]) + (p[2] + p[3]);
            const float s1 = (p[4] + p[5]) + (p[6] + p[7]);
            const float s2 = (p[8] + p[9]) + (p[10] + p[11]);
            const float s3 = (p[12] + p[13]) + (p[14] + p[15]);
            lsum[ph] += (s0 + s1) + (s2 + s3);
        }
        // P -> LDS (row l16, chunk-swizzled), same-wave readback
#pragma unroll
        for (int t = 0; t < 4; t++) {
            uint2 pk;
            pk.x = pack_bf16_ru(p[t * 4 + 0], p[t * 4 + 1]);
            pk.y = pack_bf16_ru(p[t * 4 + 2], p[t * 4 + 3]);
            const int pc = ((2 * t + (quad >> 1)) ^ l7) * 8 + (quad & 1) * 4;
            *(uint2*)(Pw + l16 * 64 + pc) = pk;
        }
#pragma unroll
        for (int kg = 0; kg < 2; kg++) {
            short8 pf = *(const short8*)(Pw + l16 * 64 + (((kg * 4 + quad) ^ l7) * 8));
#pragma unroll
            for (int dg = 0; dg < 4; dg++)
                o[ph][dg] = __builtin_amdgcn_mfma_f32_16x16x32_bf16(vf[kg][dg], pf, o[ph][dg], 0, 0, 0);
        }
    }
#undef STAGE

    // final l reduction across quads (same q column), then store O^T
#pragma unroll
    for (int ph = 0; ph < 2; ph++) {
        float l = lsum[ph];
        l += __shfl_xor(l, 16);
        l += __shfl_xor(l, 32);
        const float rinv = 1.f / l;
        float* op = out + ((size_t)(b * 2048 + qb[ph] + l16)) * 1024 + h * 64;
#pragma unroll
        for (int dg = 0; dg < 4; dg++) {
            float4 v;
            v.x = o[ph][dg][0] * rinv; v.y = o[ph][dg][1] * rinv;
            v.z = o[ph][dg][2] * rinv; v.w = o[ph][dg][3] * rinv;
            *(float4*)(op + dg * 16 + quad * 4) = v;
        }
    }
}

// ---------------- launch ----------------
extern "C" void kernel_launch(void* const* d_in, const int* in_sizes, int n_in,
                              void* d_out, int out_size, void* d_ws, size_t ws_size,
                              hipStream_t stream) {
    const float* x    = (const float*)d_in[0];
    const float* w    = (const float*)d_in[1];
    const float* bias = (const float*)d_in[2];

    ushort* xb  = (ushort*)d_ws;                 // 8192x1024 bf16
    ushort* wb  = xb + 8388608;                  // 3072x1024 bf16
    ushort* Qb  = wb + 3145728;                  // [B,H,T,D] (pre-scaled)
    ushort* Kb  = Qb + 8388608;                  // [B,H,T,D]
    ushort* Vtb = Kb + 8388608;                  // [B,H,D,T]

    cvt_all<<<11264, 256, 0, stream>>>(x, w, xb, wb);
    qkv_gemm<<<1536, 256, 0, stream>>>(xb, wb, bias, Qb, Kb, Vtb);
    attn_fwd<<<1024, 256, 0, stream>>>(Qb, Kb, Vtb, (float*)d_out);
}

// Round 7
// 231.729 us; speedup vs baseline: 2.0206x; 2.0206x over previous
//
#include <hip/hip_runtime.h>
#include <math.h>

// Causal self-attention, B=4 T=2048 E=1024 H=16 D=64.
// R14: qkv_gemm = R7 verbatim (79us, twice-proven). cvt unchanged.
//   attn_fwd: R13's paired 64-row q-tiles KEPT (every block = 33 key-tiles ->
//   4 equal blocks/CU, LDS 4x40KB = 160KiB exactly), but the R13 4x regression
//   was rule #20: runtime `ph` indexed o[ph]/qf[ph]/lsum[ph] -> accumulators
//   went to SCRATCH (VALUBusy ~50% of a 4x-longer kernel = 4x VALU ops; VGPR
//   dropped 96->92). Fix: split the tile loop into two compile-time phases;
//   all per-phase state is named registers (oA/oB, qfA/qfB, lsA/lsB).
//   Phase-A's last prefetch chains to phase-B tile 0 (33 stages, 33 barriers,
//   dbuf parity preserved). Mask branch wave-uniform, fires only on each
//   phase's last tile. Tree-sum kept. No setprio (R11: harmful here).

using short8 = __attribute__((ext_vector_type(8))) short;
using f32x4  = __attribute__((ext_vector_type(4))) float;

__device__ __forceinline__ ushort f2bf(float f) {
    union { float f; unsigned u; } x{f};
    unsigned r = x.u + 0x7fffu + ((x.u >> 16) & 1u);   // RNE
    return (ushort)(r >> 16);
}
// pack two f32 -> two bf16 (round-half-up in magnitude; <=1 ulp) in 3 VALU
__device__ __forceinline__ unsigned pack_bf16_ru(float a, float b) {
    union { float f; unsigned u; } x{a}, y{b};
    return __builtin_amdgcn_perm(y.u + 0x8000u, x.u + 0x8000u, 0x07060302u);
}

__device__ __forceinline__ void gload_lds16(const void* g, void* l) {
    __builtin_amdgcn_global_load_lds(
        (const __attribute__((address_space(1))) void*)g,
        (__attribute__((address_space(3))) void*)l, 16, 0, 0);
}

// ---------------- fp32 -> bf16 convert (x and w in one launch) ----------------
__global__ void cvt_all(const float* __restrict__ x, const float* __restrict__ w,
                        ushort* __restrict__ xb, ushort* __restrict__ wb) {
    int i = blockIdx.x * blockDim.x + threadIdx.x;
    const float* src; ushort* dst; int j;
    if (i < 2097152) { src = x; dst = xb; j = i; }
    else             { src = w; dst = wb; j = i - 2097152; if (j >= 786432) return; }
    float4 v = ((const float4*)src)[j];
    ushort4 o;
    o.x = f2bf(v.x); o.y = f2bf(v.y); o.z = f2bf(v.z); o.w = f2bf(v.w);
    ((ushort4*)dst)[j] = o;
}

// ---------------- QKV GEMM ----------------
// M=8192 N=3072 K=1024. 128x128 tile, BK=64, global_load_lds + swizzle.
// Grid 1536 1-D: xcd=id&7 owns bm slab xcd*8..+7 (A-tiles filled once per L2).
__global__ __launch_bounds__(256) void qkv_gemm(
    const ushort* __restrict__ A, const ushort* __restrict__ W,
    const float* __restrict__ bias,
    ushort* __restrict__ Qo, ushort* __restrict__ Ko, ushort* __restrict__ Vt)
{
    __shared__ ushort As[128 * 64];
    __shared__ ushort Ws[128 * 64];
    const int id = (int)blockIdx.x;
    const int xcd = id & 7, s = id >> 3;          // s: 0..191
    const int bm = xcd * 8 + (s & 7);             // 8-row slab per XCD
    const int bn = s >> 3;                        // 0..23
    const int tid = threadIdx.x;
    const int wave = tid >> 6, lane = tid & 63;
    const int quad = lane >> 4, l16 = lane & 15, l7 = l16 & 7;
    const int wm = (wave >> 1) * 64, wn = (wave & 1) * 64;

    const ushort* Abase = A + (size_t)(bm * 128) * 1024;
    const ushort* Wbase = W + (size_t)(bn * 128) * 1024;

    f32x4 acc[4][4];
#pragma unroll
    for (int i = 0; i < 4; i++)
#pragma unroll
        for (int j = 0; j < 4; j++) acc[i][j] = (f32x4){0.f, 0.f, 0.f, 0.f};

    for (int k0 = 0; k0 < 1024; k0 += 64) {
        __syncthreads();
#pragma unroll
        for (int j = 0; j < 4; j++) {
            const int rb = wave * 32 + j * 8;
            const int r  = rb + (lane >> 3);
            const int cc = (lane & 7) ^ (r & 7);
            gload_lds16(Abase + (size_t)r * 1024 + k0 + cc * 8, &As[rb * 64]);
            gload_lds16(Wbase + (size_t)r * 1024 + k0 + cc * 8, &Ws[rb * 64]);
        }
        __syncthreads();
        short8 af[4][2], wf[4][2];
#pragma unroll
        for (int t = 0; t < 4; t++)
#pragma unroll
            for (int kg = 0; kg < 2; kg++) {
                const int pc = ((kg * 4 + quad) ^ l7) * 8;
                af[t][kg] = *(const short8*)&As[(wm + t * 16 + l16) * 64 + pc];
                wf[t][kg] = *(const short8*)&Ws[(wn + t * 16 + l16) * 64 + pc];
            }
#pragma unroll
        for (int kg = 0; kg < 2; kg++)
#pragma unroll
            for (int tm = 0; tm < 4; tm++)
#pragma unroll
                for (int tn = 0; tn < 4; tn++)
                    acc[tm][tn] = __builtin_amdgcn_mfma_f32_16x16x32_bf16(af[tm][kg], wf[tn][kg], acc[tm][tn], 0, 0, 0);
    }

    const float SCALE_Q = 0.125f * 1.4426950408889634f;
#pragma unroll
    for (int tn = 0; tn < 4; tn++) {
        const int n = bn * 128 + wn + tn * 16 + l16;
        const float bv = bias[n];
#pragma unroll
        for (int tm = 0; tm < 4; tm++) {
            const int m0 = bm * 128 + wm + tm * 16 + quad * 4;
            const int b0 = m0 >> 11, t0 = m0 & 2047;
            if (n < 1024) {
                const int h = n >> 6, d = n & 63;
#pragma unroll
                for (int r = 0; r < 4; r++)
                    Qo[((size_t)(b0 * 16 + h) * 2048 + t0 + r) * 64 + d] = f2bf((acc[tm][tn][r] + bv) * SCALE_Q);
            } else if (n < 2048) {
                const int c = n - 1024, h = c >> 6, d = c & 63;
#pragma unroll
                for (int r = 0; r < 4; r++)
                    Ko[((size_t)(b0 * 16 + h) * 2048 + t0 + r) * 64 + d] = f2bf(acc[tm][tn][r] + bv);
            } else {
                const int c = n - 2048, h = c >> 6, d = c & 63;
                uint2 pk;
                pk.x = pack_bf16_ru(acc[tm][tn][0] + bv, acc[tm][tn][1] + bv);
                pk.y = pack_bf16_ru(acc[tm][tn][2] + bv, acc[tm][tn][3] + bv);
                *(uint2*)&Vt[((size_t)(b0 * 16 + h) * 64 + d) * 2048 + t0] = pk;
            }
        }
    }
}

// ---------------- Flash attention (fixed-max softmax, paired 64-row q-tiles) ----------------
// 1024 blocks: bh = id&63 (id%8 = bh%8 -> head's blocks on one XCD), pr = id>>6.
// Block handles q-tiles qtA=pr and qtB=31-pr: key-tiles = (pr+1)+(32-pr) = 33
// for EVERY block -> 4 equal blocks/CU all kernel long (LDS 4x40KB = 160KiB).
// Phases are COMPILE-TIME (two loops); per-phase state in named registers.
__global__ __launch_bounds__(256) void attn_fwd(
    const ushort* __restrict__ Q, const ushort* __restrict__ K,
    const ushort* __restrict__ Vt, float* __restrict__ out)
{
    __shared__ ushort Ks[2][64 * 64];
    __shared__ ushort Vs[2][64 * 64];
    __shared__ ushort Ps[4][16 * 64];   // per-wave
    const int id = (int)blockIdx.x;     // 1024 blocks
    const int bh = id & 63;
    const int pr = id >> 6;             // 0..15
    const int na = pr + 1;              // phase-A tiles (q-tile pr)
    const int nb = 32 - pr;             // phase-B tiles (q-tile 31-pr); na+nb=33
    const int b = bh >> 4, h = bh & 15;
    const int wave = threadIdx.x >> 6, lane = threadIdx.x & 63;
    const int quad = lane >> 4, l16 = lane & 15, l7 = l16 & 7;

    const ushort* Kbh = K  + (size_t)bh * 2048 * 64;
    const ushort* Vbh = Vt + (size_t)bh * 64 * 2048;
    ushort* Pw = Ps[wave];

    const int qbA = pr * 64 + wave * 16;
    const int qbB = (31 - pr) * 64 + wave * 16;

    short8 qfA[2], qfB[2];
    {
        const ushort* Qp = Q + ((size_t)bh * 2048 + qbA + l16) * 64;
        qfA[0] = *(const short8*)(Qp + quad * 8);
        qfA[1] = *(const short8*)(Qp + 32 + quad * 8);
        const ushort* Qq = Q + ((size_t)bh * 2048 + qbB + l16) * 64;
        qfB[0] = *(const short8*)(Qq + quad * 8);
        qfB[1] = *(const short8*)(Qq + 32 + quad * 8);
    }

    f32x4 oA[4], oB[4];
#pragma unroll
    for (int dg = 0; dg < 4; dg++) {
        oA[dg] = (f32x4){0.f, 0.f, 0.f, 0.f};
        oB[dg] = (f32x4){0.f, 0.f, 0.f, 0.f};
    }
    float lsA = 0.f, lsB = 0.f;

#define STAGE(k0_, bf_)                                                              \
    {                                                                                \
        _Pragma("unroll")                                                            \
        for (int j = 0; j < 2; j++) {                                                \
            const int rb = wave * 16 + j * 8;                                        \
            const int r  = rb + (lane >> 3);                                         \
            const int cc = (lane & 7) ^ (r & 7);                                     \
            gload_lds16(Kbh + (size_t)((k0_) + r) * 64 + cc * 8, &Ks[bf_][rb * 64]); \
            gload_lds16(Vbh + (size_t)r * 2048 + (k0_) + cc * 8, &Vs[bf_][rb * 64]); \
        }                                                                            \
    }

    // Full tile body with compile-time-named per-phase state.
#define TILE(K0, QBX, QFX, LSX, OX)                                                  \
    {                                                                                \
        short8 kf[4][2];                                                             \
        _Pragma("unroll")                                                            \
        for (int t = 0; t < 4; t++)                                                  \
            _Pragma("unroll")                                                        \
            for (int dh = 0; dh < 2; dh++)                                           \
                kf[t][dh] = *(const short8*)&Ks[buf][(t * 16 + l16) * 64 + (((dh * 4 + quad) ^ l7) * 8)]; \
        short8 vf[2][4];                                                             \
        _Pragma("unroll")                                                            \
        for (int kg = 0; kg < 2; kg++) {                                             \
            const int pc = ((kg * 4 + quad) ^ l7) * 8;                               \
            _Pragma("unroll")                                                        \
            for (int dg = 0; dg < 4; dg++)                                           \
                vf[kg][dg] = *(const short8*)&Vs[buf][(dg * 16 + l16) * 64 + pc];    \
        }                                                                            \
        f32x4 sc[4];                                                                 \
        _Pragma("unroll")                                                            \
        for (int t = 0; t < 4; t++) {                                                \
            f32x4 z = (f32x4){0.f, 0.f, 0.f, 0.f};                                   \
            z = __builtin_amdgcn_mfma_f32_16x16x32_bf16(kf[t][0], QFX[0], z, 0, 0, 0); \
            z = __builtin_amdgcn_mfma_f32_16x16x32_bf16(kf[t][1], QFX[1], z, 0, 0, 0); \
            sc[t] = z;                                                               \
        }                                                                            \
        const int q_ = (QBX) + l16;                                                  \
        float p[16];                                                                 \
        if ((K0) + 63 > (QBX)) {      /* wave-uniform: only the phase's last tile */ \
            _Pragma("unroll")                                                        \
            for (int t = 0; t < 4; t++)                                              \
                _Pragma("unroll")                                                    \
                for (int r = 0; r < 4; r++) {                                        \
                    const int key = (K0) + t * 16 + quad * 4 + r;                    \
                    const float sv = (key <= q_) ? sc[t][r] : -INFINITY;             \
                    p[t * 4 + r] = __builtin_amdgcn_exp2f(sv);                       \
                }                                                                    \
        } else {                                                                     \
            _Pragma("unroll")                                                        \
            for (int t = 0; t < 4; t++)                                              \
                _Pragma("unroll")                                                    \
                for (int r = 0; r < 4; r++)                                          \
                    p[t * 4 + r] = __builtin_amdgcn_exp2f(sc[t][r]);                 \
        }                                                                            \
        {                                                                            \
            const float s0_ = (p[0] + p[1]) + (p[2] + p[3]);                         \
            const float s1_ = (p[4] + p[5]) + (p[6] + p[7]);                         \
            const float s2_ = (p[8] + p[9]) + (p[10] + p[11]);                       \
            const float s3_ = (p[12] + p[13]) + (p[14] + p[15]);                     \
            (LSX) += (s0_ + s1_) + (s2_ + s3_);                                      \
        }                                                                            \
        _Pragma("unroll")                                                            \
        for (int t = 0; t < 4; t++) {                                                \
            uint2 pk;                                                                \
            pk.x = pack_bf16_ru(p[t * 4 + 0], p[t * 4 + 1]);                         \
            pk.y = pack_bf16_ru(p[t * 4 + 2], p[t * 4 + 3]);                         \
            const int pc = ((2 * t + (quad >> 1)) ^ l7) * 8 + (quad & 1) * 4;        \
            *(uint2*)(Pw + l16 * 64 + pc) = pk;                                      \
        }                                                                            \
        _Pragma("unroll")                                                            \
        for (int kg = 0; kg < 2; kg++) {                                             \
            short8 pf = *(const short8*)(Pw + l16 * 64 + (((kg * 4 + quad) ^ l7) * 8)); \
            _Pragma("unroll")                                                        \
            for (int dg = 0; dg < 4; dg++)                                           \
                OX[dg] = __builtin_amdgcn_mfma_f32_16x16x32_bf16(vf[kg][dg], pf, OX[dg], 0, 0, 0); \
        }                                                                            \
    }

    STAGE(0, 0);
    int buf = 0;
    // Phase A (q-tile pr): tiles 0..na-1. Last prefetch chains to phase-B tile 0.
    for (int i = 0; i < na; ++i, buf ^= 1) {
        const int k0 = i * 64;
        __syncthreads();
        const int nk0 = (i + 1 < na) ? (i + 1) * 64 : 0;   // phase B always nonempty
        STAGE(nk0, buf ^ 1);
        TILE(k0, qbA, qfA, lsA, oA);
    }
    // Phase B (q-tile 31-pr): tiles 0..nb-1.
    for (int i = 0; i < nb; ++i, buf ^= 1) {
        const int k0 = i * 64;
        __syncthreads();
        if (i + 1 < nb) STAGE((i + 1) * 64, buf ^ 1);
        TILE(k0, qbB, qfB, lsB, oB);
    }
#undef STAGE
#undef TILE

    // final l reduction across quads (same q column), then store O^T
    {
        float l = lsA;
        l += __shfl_xor(l, 16);
        l += __shfl_xor(l, 32);
        const float rinv = 1.f / l;
        float* op = out + ((size_t)(b * 2048 + qbA + l16)) * 1024 + h * 64;
#pragma unroll
        for (int dg = 0; dg < 4; dg++) {
            float4 v;
            v.x = oA[dg][0] * rinv; v.y = oA[dg][1] * rinv;
            v.z = oA[dg][2] * rinv; v.w = oA[dg][3] * rinv;
            *(float4*)(op + dg * 16 + quad * 4) = v;
        }
    }
    {
        float l = lsB;
        l += __shfl_xor(l, 16);
        l += __shfl_xor(l, 32);
        const float rinv = 1.f / l;
        float* op = out + ((size_t)(b * 2048 + qbB + l16)) * 1024 + h * 64;
#pragma unroll
        for (int dg = 0; dg < 4; dg++) {
            float4 v;
            v.x = oB[dg][0] * rinv; v.y = oB[dg][1] * rinv;
            v.z = oB[dg][2] * rinv; v.w = oB[dg][3] * rinv;
            *(float4*)(op + dg * 16 + quad * 4) = v;
        }
    }
}

// ---------------- launch ----------------
extern "C" void kernel_launch(void* const* d_in, const int* in_sizes, int n_in,
                              void* d_out, int out_size, void* d_ws, size_t ws_size,
                              hipStream_t stream) {
    const float* x    = (const float*)d_in[0];
    const float* w    = (const float*)d_in[1];
    const float* bias = (const float*)d_in[2];

    ushort* xb  = (ushort*)d_ws;                 // 8192x1024 bf16
    ushort* wb  = xb + 8388608;                  // 3072x1024 bf16
    ushort* Qb  = wb + 3145728;                  // [B,H,T,D] (pre-scaled)
    ushort* Kb  = Qb + 8388608;                  // [B,H,T,D]
    ushort* Vtb = Kb + 8388608;                  // [B,H,D,T]

    cvt_all<<<11264, 256, 0, stream>>>(x, w, xb, wb);
    qkv_gemm<<<1536, 256, 0, stream>>>(xb, wb, bias, Qb, Kb, Vtb);
    attn_fwd<<<1024, 256, 0, stream>>>(Qb, Kb, Vtb, (float*)d_out);
}